// Round 9
// baseline (297.620 us; speedup 1.0000x reference)
//
#include <hip/hip_runtime.h>

#define BATCH   1024
#define MSIZE   65536
#define KDIM    256
#define CHOOSEK 128
#define SELK    160        // suffix-count crossing target
#define CAP     4096       // per-row candidate-list capacity (expected ~2300; overflow -> dense fallback)
#define BETA    1e-8f
#define ALPHA   0.5f
// u8 key = clamp((sim + log(hist+beta) + KOFF) * KSC). Monotone in score (log map, no exp).
// bytes>=128 ~ 2300/row (integral of Phi over uniform hist); threshold byte ~165-175.
// bucket = 1/425 log-units vs bf16 screening error ~2.5e-4 -> wide superset margin.
#define KSC  425.0f
#define KOFF 7.2f

typedef short bf16x8 __attribute__((ext_vector_type(8)));
typedef float f32x4  __attribute__((ext_vector_type(4)));

__device__ inline unsigned int pack2bf(float a, float b) {   // RNE fp32->bf16 pair
    unsigned int ua = __float_as_uint(a);
    unsigned int ub = __float_as_uint(b);
    ua += 0x7fffu + ((ua >> 16) & 1u);
    ub += 0x7fffu + ((ub >> 16) & 1u);
    return (ua >> 16) | (ub & 0xffff0000u);
}

// async global->LDS, 16B/lane; LDS dest is wave-uniform base + lane*16 (must be linear in tid)
#define GLD16(g, l) __builtin_amdgcn_global_load_lds( \
    (const __attribute__((address_space(1))) unsigned int*)(g), \
    (__attribute__((address_space(3))) unsigned int*)(l), 16, 0, 0)

// -------------------------------------------------------------------------
// Kernel 0: one-time preprocessing.
//  blocks [0,8192):     key fp32 -> bf16 (kb)
//  blocks [8192,8320):  q fp32 -> bf16 in FRAGMENT order (see r7/r8)
//  blocks [8320,8576):  L[n] = (log(hist[n]+BETA)+KOFF)*KSC
//  block  8576:         zero the per-row candidate counters (every launch)
// -------------------------------------------------------------------------
__global__ __launch_bounds__(256)
void convert_kernel(const float* __restrict__ q, const float* __restrict__ key,
                    const float* __restrict__ hist,
                    unsigned short* __restrict__ qs, unsigned short* __restrict__ kb,
                    float* __restrict__ Ltab, unsigned int* __restrict__ gcnt)
{
    const int bid = blockIdx.x, tid = threadIdx.x;
    if (bid < 8192) {                       // key convert
        const int off = bid * 256 + tid;
        const float4* s4 = (const float4*)key;
        float4 a = s4[off * 2], b = s4[off * 2 + 1];
        ((uint4*)kb)[off] = make_uint4(pack2bf(a.x, a.y), pack2bf(a.z, a.w),
                                       pack2bf(b.x, b.y), pack2bf(b.z, b.w));
    } else if (bid < 8320) {                // q fragment-swizzle
        const int f = (bid - 8192) * 256 + tid;
        const int l = f & 63, j = (f >> 6) & 3, ks = (f >> 8) & 7;
        const int wmg = (f >> 11) & 3, bt = (f >> 13) & 3;
        const int r = bt * 256 + wmg * 64 + j * 16 + (l & 15);
        const int c = ks * 32 + (l >> 4) * 8;
        const float* src = q + (size_t)r * KDIM + c;
        float4 a = *(const float4*)src, b = *(const float4*)(src + 4);
        ((uint4*)qs)[f] = make_uint4(pack2bf(a.x, a.y), pack2bf(a.z, a.w),
                                     pack2bf(b.x, b.y), pack2bf(b.z, b.w));
    } else if (bid < 8576) {                // L table
        const int n = (bid - 8320) * 256 + tid;
        Ltab[n] = (logf(hist[n] + BETA) + KOFF) * KSC;
    } else {                                // zero candidate counters
        gcnt[tid] = 0u; gcnt[tid + 256] = 0u;
        gcnt[tid + 512] = 0u; gcnt[tid + 768] = 0u;
    }
}

// -------------------------------------------------------------------------
// Kernel 1: bf16 screening GEMM (r8 structure, unchanged K-loop):
// 256x128 tile, 512 thr (8 waves 4m x 2n), BK=32, 3-buf B ring, counted
// vmcnt(1), one-step-ahead qf register pipeline, setprio on MFMA cluster.
// Epilogue: byte = clamp(fma(sim, KSC, L[n])), packed dword store to dense s8
// (sound fallback for select), PLUS sparse append: bytes >= 128 go to the
// per-row global candidate list (entry = byte<<16 | mem_idx). ~2 atomics/lane.
// -------------------------------------------------------------------------
__global__ __launch_bounds__(512, 4)
void score_kernel(const unsigned short* __restrict__ qs,
                  const unsigned short* __restrict__ kb,
                  const float* __restrict__ Ltab,
                  unsigned char* __restrict__ s8,
                  unsigned int* __restrict__ gcnt,
                  unsigned int* __restrict__ glist)
{
    __shared__ __align__(16) unsigned short Bs[3][128 * 32];   // 3 x 8 KB
    const int tid = threadIdx.x;
    const int bid = blockIdx.x;
    const int bt = (bid >> 3) & 3;
    const int b0 = bt * 256;                               // batch tile (4)
    const int n0 = ((bid & 7) + ((bid >> 5) << 3)) * 128;  // memory tile (512), XCD-grouped
    const int lane = tid & 63, wave = tid >> 6;
    const int wm = (wave >> 1) * 64, wn = (wave & 1) * 64;
    const int l15 = lane & 15, l4 = lane >> 4;
    const int wmg = wave >> 1;

    f32x4 acc[4][4] = {};

    const int srow = tid >> 2;          // 0..127
    const int seg  = (tid & 3) * 8;
    const unsigned short* gB = kb + (size_t)(n0 + srow) * KDIM + seg;
    const int lofs = srow * 32 + seg;   // byte offset tid*16: linear per wave

    // per-wave fragment base: qw[(s*4+j)*64] is this lane's 16B A-fragment
    const bf16x8* qw = (const bf16x8*)qs + (size_t)((bt * 4 + wmg) * 32) * 64 + lane;

    bf16x8 qf[2][4];

#define STAGE_B(st) GLD16(gB + (st) * 32, &Bs[(st) % 3][lofs])

#define STEP(s, WN) do {                                                          \
    asm volatile("s_waitcnt vmcnt(" #WN ")" ::: "memory");                        \
    __builtin_amdgcn_s_barrier();                                                 \
    asm volatile("" ::: "memory");                                                \
    if ((s) < 7) {                                                                \
        _Pragma("unroll")                                                         \
        for (int j = 0; j < 4; ++j)                                               \
            qf[((s) + 1) & 1][j] = qw[(((s) + 1) * 4 + j) * 64];                  \
    }                                                                             \
    if ((s) + 2 < 8) STAGE_B((s) + 2);                                            \
    bf16x8 kf[4];                                                                 \
    _Pragma("unroll")                                                             \
    for (int i = 0; i < 4; ++i)                                                   \
        kf[i] = *(const bf16x8*)(&Bs[(s) % 3][(wn + i * 16 + l15) * 32 + l4 * 8]);\
    __builtin_amdgcn_s_setprio(1);                                                \
    _Pragma("unroll")                                                             \
    for (int i = 0; i < 4; ++i)                                                   \
        _Pragma("unroll")                                                         \
        for (int j = 0; j < 4; ++j)                                               \
            acc[i][j] = __builtin_amdgcn_mfma_f32_16x16x32_bf16(kf[i], qf[(s) & 1][j], acc[i][j], 0, 0, 0); \
    __builtin_amdgcn_s_setprio(0);                                                \
} while (0)

    // prologue: qf step 0 first (older than stages in vmcnt queue), then B 0,1
#pragma unroll
    for (int j = 0; j < 4; ++j) qf[0][j] = qw[j * 64];
    STAGE_B(0); STAGE_B(1);

    STEP(0, 1); STEP(1, 1); STEP(2, 1); STEP(3, 1);
    STEP(4, 1); STEP(5, 1); STEP(6, 1); STEP(7, 0);

#undef STEP
#undef STAGE_B

    // epilogue: within acc[i][j]: mem = n0+wn+i*16+l4*4+reg, batch = b0+wm+j*16+l15
    float4 Lv[4];
#pragma unroll
    for (int i = 0; i < 4; ++i)
        Lv[i] = *(const float4*)&Ltab[n0 + wn + i * 16 + l4 * 4];
#pragma unroll
    for (int j = 0; j < 4; ++j) {
        const int rb = b0 + wm + j * 16 + l15;
        const size_t row = (size_t)rb * MSIZE;
#pragma unroll
        for (int i = 0; i < 4; ++i) {
            const float* lv = (const float*)&Lv[i];
            const int nb = n0 + wn + i * 16 + l4 * 4;
            unsigned int pk = 0;
#pragma unroll
            for (int reg = 0; reg < 4; ++reg) {
                float x = fmaf(acc[i][j][reg], KSC, lv[reg]);
                x = fminf(fmaxf(x, 0.0f), 255.0f);
                pk |= (unsigned int)(int)x << (8 * reg);
            }
            *(unsigned int*)(s8 + row + nb) = pk;
            // sparse append: bytes >= 128 -> per-row candidate list
            unsigned int m = pk & 0x80808080u;
            if (m) {
                int c = __popc(m);
                unsigned int base = atomicAdd(&gcnt[rb], (unsigned int)c);
                unsigned int pos = 0;
#pragma unroll
                for (int reg = 0; reg < 4; ++reg) {
                    unsigned int by = (pk >> (8 * reg)) & 0xffu;
                    if (by & 0x80u) {
                        unsigned int slot = base + pos;
                        if (slot < CAP)
                            glist[(size_t)rb * CAP + slot] = (by << 16) | (unsigned int)(nb + reg);
                        ++pos;
                    }
                }
            }
        }
    }
}

// -------------------------------------------------------------------------
// Kernel 2: per batch row.
//   FAST PATH (expected always): read this row's candidate list (~2300
//   entries, 9 KB) -- no 64 KB row stream at all. Histogram list bytes,
//   suffix-scan -> H (crossing SELK), collect entries >= H.
//   DENSE FALLBACK (list overflow or < SELK entries): full-stream histogram
//   + collect over the dense s8 row (sound for any data).
//   Then: 16-lane-group exact fp32 rescore; count-based exact top-128
//   (ties -> lower index); weighted sum.  Identical selection semantics.
// -------------------------------------------------------------------------
__global__ __launch_bounds__(256, 4)
void select_kernel(const float* __restrict__ q,
                   const float* __restrict__ key,
                   const float* __restrict__ hist,
                   const float* __restrict__ vals,
                   const unsigned char* __restrict__ s8,
                   const unsigned int* __restrict__ gcnt,
                   const unsigned int* __restrict__ glist,
                   float* __restrict__ out)
{
    const int b   = blockIdx.x;
    const int tid = threadIdx.x;

    __shared__ __align__(16) float qs[KDIM];
    __shared__ unsigned int hcnt[16 * 257];   // 16 replicated histograms
    __shared__ int   stot[256];
    __shared__ int   scal[2];                 // 0:H  1:ncand
    __shared__ int   cidx[1024];
    __shared__ float csc[1024], cjj[1024], cjv[1024];
    __shared__ float wred[8];

    qs[tid] = q[(size_t)b * KDIM + tid];
    const uint4* rowp = reinterpret_cast<const uint4*>(s8 + (size_t)b * MSIZE);
    const unsigned int* gl = glist + (size_t)b * CAP;
    const int rep = (tid & 15) * 257;

    const int nl = (int)gcnt[b];
    int mode = (nl <= CAP) ? 0 : 1;           // 0 = list, 1 = dense fallback

    // ---- threshold search ----
    int H = -1;
    for (;;) {
        for (int i = tid; i < 16 * 257; i += 256) hcnt[i] = 0u;
        if (tid == 0) { scal[0] = -1; scal[1] = 0; }
        __syncthreads();

        if (mode == 0) {
            for (int i = tid; i < nl; i += 256)
                atomicAdd(&hcnt[rep + (gl[i] >> 16)], 1u);
        } else {
            for (int i = 0; i < 16; ++i) {
                uint4 v = rowp[i * 256 + tid];
                unsigned int w[4] = {v.x, v.y, v.z, v.w};
#pragma unroll
                for (int k = 0; k < 4; ++k) {
#pragma unroll
                    for (int jj = 0; jj < 4; ++jj)
                        atomicAdd(&hcnt[rep + ((w[k] >> (8 * jj)) & 0xffu)], 1u);
                }
            }
        }
        __syncthreads();
        { unsigned int t = 0;
#pragma unroll
          for (int k = 0; k < 16; ++k) t += hcnt[k * 257 + tid];
          stot[tid] = (int)t; }
        __syncthreads();

        // single-wave suffix scan over 256 bins; find crossing S[b]>=SELK>S[b+1]
        if (tid < 64) {
            const int l = tid;
            int t0 = stot[l * 4], t1 = stot[l * 4 + 1], t2 = stot[l * 4 + 2], t3 = stot[l * 4 + 3];
            int lsum = t0 + t1 + t2 + t3;
            int s = lsum;
#pragma unroll
            for (int off = 1; off < 64; off <<= 1) {
                int u = __shfl_down(s, off, 64);
                if (l + off < 64) s += u;
            }
            int A  = s - lsum;        // sum over lanes > l (== S[4l+4])
            int S3 = A + t3;
            int S2 = S3 + t2;
            int S1 = S2 + t1;
            int S0 = S1 + t0;
            if (S0 >= SELK && S1 < SELK) scal[0] = l * 4 + 0;
            if (S1 >= SELK && S2 < SELK) scal[0] = l * 4 + 1;
            if (S2 >= SELK && S3 < SELK) scal[0] = l * 4 + 2;
            if (S3 >= SELK && A  < SELK) scal[0] = l * 4 + 3;
        }
        __syncthreads();
        H = scal[0];
        __syncthreads();              // all threads read H before next-iter rewrites
        if (H >= 0) break;
        mode = 1;                     // list had < SELK entries: dense re-run
    }

    // ---- collect candidates (byte >= H) ----
    const unsigned int uH = (unsigned int)H;
    if (mode == 0) {
        for (int i = tid; i < nl; i += 256) {
            unsigned int e = gl[i];
            if ((e >> 16) >= uH) {
                int p = atomicAdd(&scal[1], 1);
                if (p < 1024) cidx[p] = (int)(e & 0xffffu);
            }
        }
    } else {
        for (int i = 0; i < 16; ++i) {
            uint4 v = rowp[i * 256 + tid];
            const int base = (i * 256 + tid) * 16;
            unsigned int w[4] = {v.x, v.y, v.z, v.w};
#pragma unroll
            for (int k = 0; k < 4; ++k) {
#pragma unroll
                for (int jj = 0; jj < 4; ++jj) {
                    unsigned int bb = (w[k] >> (8 * jj)) & 0xffu;
                    if (bb >= uH) {
                        int p = atomicAdd(&scal[1], 1);
                        if (p < 1024) cidx[p] = base + 4 * k + jj;
                    }
                }
            }
        }
    }
    __syncthreads();
    const int ncand = min(scal[1], 1024);

    // ---- exact fp32 rescore: 16-lane groups, 4 candidates per wave in flight ----
    const int gid = tid >> 4, gll = tid & 15;
    const float4* q4 = (const float4*)qs;
    for (int i = gid; i < ncand; i += 16) {
        const int idx = cidx[i];
        const float4* kp = (const float4*)(key + (size_t)idx * KDIM);
        float p = 0.f;
#pragma unroll
        for (int u = 0; u < 4; ++u) {
            float4 kk = kp[gll * 4 + u];
            float4 qq = q4[gll * 4 + u];
            p += kk.x * qq.x + kk.y * qq.y + kk.z * qq.z + kk.w * qq.w;
        }
#pragma unroll
        for (int off = 1; off < 16; off <<= 1) p += __shfl_xor(p, off, 64);
        if (gll == 0) {
            float e = expf(p - 1.0f);
            float h = hist[idx];
            csc[i] = e * (h + BETA);
            float j = e * (ALPHA * h + BETA);
            cjj[i] = j;
            cjv[i] = j * vals[idx];
        }
    }
    __syncthreads();

    // ---- exact top-128 among candidates (count-based; ties -> lower index) ----
    const int wave = tid >> 6, lane = tid & 63;
    float pn = 0.f, pd = 0.f;
    for (int i = tid; i < ncand; i += 256) {
        float si = csc[i]; int ii = cidx[i]; int rank = 0;
        for (int t = 0; t < ncand; ++t) {
            float st = csc[t];
            rank += (st > si || (st == si && cidx[t] < ii)) ? 1 : 0;
        }
        if (rank < CHOOSEK) { pn += cjv[i]; pd += cjj[i]; }
    }
#pragma unroll
    for (int off = 32; off > 0; off >>= 1) {
        pn += __shfl_xor(pn, off, 64);
        pd += __shfl_xor(pd, off, 64);
    }
    if (lane == 0) { wred[wave] = pn; wred[4 + wave] = pd; }
    __syncthreads();
    if (tid == 0) {
        float n = wred[0] + wred[1] + wred[2] + wred[3];
        float d = wred[4] + wred[5] + wred[6] + wred[7];
        out[b] = n / d;
    }
}

// -------------------------------------------------------------------------
extern "C" void kernel_launch(void* const* d_in, const int* in_sizes, int n_in,
                              void* d_out, int out_size, void* d_ws, size_t ws_size,
                              hipStream_t stream)
{
    (void)in_sizes; (void)n_in; (void)out_size; (void)ws_size;
    const float* q    = (const float*)d_in[0];
    const float* key  = (const float*)d_in[1];
    const float* hist = (const float*)d_in[2];
    const float* vals = (const float*)d_in[3];
    float* out = (float*)d_out;

    // workspace layout (113 MiB total):
    unsigned char*  s8 = (unsigned char*)d_ws;                                     // 64 MiB dense u8 keys
    unsigned short* kb = (unsigned short*)((char*)d_ws + ((size_t)64 << 20));      // 32 MiB bf16 key
    unsigned short* qsw= (unsigned short*)((char*)d_ws + ((size_t)96 << 20));      // 512 KiB bf16 q (frag order)
    float*          Lt = (float*)((char*)d_ws + ((size_t)96 << 20) + (512 << 10)); // 256 KiB L table
    unsigned int* gcnt = (unsigned int*)((char*)d_ws + ((size_t)96 << 20) + (768 << 10)); // 4 KiB counters
    unsigned int* glist= (unsigned int*)((char*)d_ws + ((size_t)97 << 20));        // 16 MiB candidate lists

    convert_kernel<<<8577, 256, 0, stream>>>(q, key, hist, qsw, kb, Lt, gcnt);
    score_kernel<<<2048, 512, 0, stream>>>(qsw, kb, Lt, s8, gcnt, glist);
    select_kernel<<<BATCH, 256, 0, stream>>>(q, key, hist, vals, s8, gcnt, glist, out);
}

// Round 10
// 203.709 us; speedup vs baseline: 1.4610x; 1.4610x over previous
//
#include <hip/hip_runtime.h>

#define BATCH   1024
#define MSIZE   65536
#define KDIM    256
#define CHOOSEK 128
#define SELK    160        // suffix-count crossing target
#define CLCAP   2816       // LDS candidate-list capacity (expected ~2300)
#define BETA    1e-8f
#define ALPHA   0.5f
// u8 key = clamp((sim + log(hist+beta) + KOFF) * KSC). Monotone in score (log map, no exp).
// bytes>=128 ~ 2300/row; threshold byte ~165-175. bucket = 1/425 log-units vs bf16
// screening error ~1e-3*425 ~ 0.5 byte -> SELK-CHOOSEK = 32 ranks (~1.5 buckets) margin.
#define KSC  425.0f
#define KOFF 7.2f

typedef short bf16x8 __attribute__((ext_vector_type(8)));
typedef float f32x4  __attribute__((ext_vector_type(4)));

__device__ inline unsigned int pack2bf(float a, float b) {   // RNE fp32->bf16 pair
    unsigned int ua = __float_as_uint(a);
    unsigned int ub = __float_as_uint(b);
    ua += 0x7fffu + ((ua >> 16) & 1u);
    ub += 0x7fffu + ((ub >> 16) & 1u);
    return (ua >> 16) | (ub & 0xffff0000u);
}

// async global->LDS, 16B/lane; LDS dest is wave-uniform base + lane*16 (must be linear in tid)
#define GLD16(g, l) __builtin_amdgcn_global_load_lds( \
    (const __attribute__((address_space(1))) unsigned int*)(g), \
    (__attribute__((address_space(3))) unsigned int*)(l), 16, 0, 0)

// -------------------------------------------------------------------------
// Kernel 0: one-time preprocessing (r8 structure, no counters needed).
//  blocks [0,8192):     key fp32 -> bf16 (kb)
//  blocks [8192,8320):  q fp32 -> bf16 in FRAGMENT order (see r7/r8)
//  blocks [8320,8576):  L[n] = (log(hist[n]+BETA)+KOFF)*KSC
// -------------------------------------------------------------------------
__global__ __launch_bounds__(256)
void convert_kernel(const float* __restrict__ q, const float* __restrict__ key,
                    const float* __restrict__ hist,
                    unsigned short* __restrict__ qs, unsigned short* __restrict__ kb,
                    float* __restrict__ Ltab)
{
    const int bid = blockIdx.x, tid = threadIdx.x;
    if (bid < 8192) {                       // key convert
        const int off = bid * 256 + tid;
        const float4* s4 = (const float4*)key;
        float4 a = s4[off * 2], b = s4[off * 2 + 1];
        ((uint4*)kb)[off] = make_uint4(pack2bf(a.x, a.y), pack2bf(a.z, a.w),
                                       pack2bf(b.x, b.y), pack2bf(b.z, b.w));
    } else if (bid < 8320) {                // q fragment-swizzle
        const int f = (bid - 8192) * 256 + tid;
        const int l = f & 63, j = (f >> 6) & 3, ks = (f >> 8) & 7;
        const int wmg = (f >> 11) & 3, bt = (f >> 13) & 3;
        const int r = bt * 256 + wmg * 64 + j * 16 + (l & 15);
        const int c = ks * 32 + (l >> 4) * 8;
        const float* src = q + (size_t)r * KDIM + c;
        float4 a = *(const float4*)src, b = *(const float4*)(src + 4);
        ((uint4*)qs)[f] = make_uint4(pack2bf(a.x, a.y), pack2bf(a.z, a.w),
                                     pack2bf(b.x, b.y), pack2bf(b.z, b.w));
    } else {                                // L table
        const int n = (bid - 8320) * 256 + tid;
        Ltab[n] = (logf(hist[n] + BETA) + KOFF) * KSC;
    }
}

// -------------------------------------------------------------------------
// Kernel 1: bf16 screening GEMM — K-loop IDENTICAL to r8 (verified 67us):
// 256x128 tile, 512 thr (8 waves 4m x 2n), BK=32, 3-buf B ring, counted
// vmcnt(1), one-step-ahead qf register pipeline, setprio on MFMA cluster.
// Epilogue: byte = clamp(fma(sim, KSC, L[n])), packed dword store to dense s8,
// PLUS atomic-free bitmask: bit n of gmask[row] = (byte n >= 128). Each mask
// u64 is OR-reduced across the 4-lane (l4) group via shfl_xor and stored by
// exactly one lane — every word written exactly once, no atomics, no zeroing.
// (r9 lesson: per-row global atomics serialized the whole kernel.)
// -------------------------------------------------------------------------
__global__ __launch_bounds__(512, 4)
void score_kernel(const unsigned short* __restrict__ qs,
                  const unsigned short* __restrict__ kb,
                  const float* __restrict__ Ltab,
                  unsigned char* __restrict__ s8,
                  unsigned long long* __restrict__ gmask)
{
    __shared__ __align__(16) unsigned short Bs[3][128 * 32];   // 3 x 8 KB
    const int tid = threadIdx.x;
    const int bid = blockIdx.x;
    const int bt = (bid >> 3) & 3;
    const int b0 = bt * 256;                               // batch tile (4)
    const int n0 = ((bid & 7) + ((bid >> 5) << 3)) * 128;  // memory tile (512), XCD-grouped
    const int lane = tid & 63, wave = tid >> 6;
    const int wm = (wave >> 1) * 64, wn = (wave & 1) * 64;
    const int l15 = lane & 15, l4 = lane >> 4;
    const int wmg = wave >> 1;

    f32x4 acc[4][4] = {};

    const int srow = tid >> 2;          // 0..127
    const int seg  = (tid & 3) * 8;
    const unsigned short* gB = kb + (size_t)(n0 + srow) * KDIM + seg;
    const int lofs = srow * 32 + seg;   // byte offset tid*16: linear per wave

    // per-wave fragment base: qw[(s*4+j)*64] is this lane's 16B A-fragment
    const bf16x8* qw = (const bf16x8*)qs + (size_t)((bt * 4 + wmg) * 32) * 64 + lane;

    bf16x8 qf[2][4];

#define STAGE_B(st) GLD16(gB + (st) * 32, &Bs[(st) % 3][lofs])

#define STEP(s, WN) do {                                                          \
    asm volatile("s_waitcnt vmcnt(" #WN ")" ::: "memory");                        \
    __builtin_amdgcn_s_barrier();                                                 \
    asm volatile("" ::: "memory");                                                \
    if ((s) < 7) {                                                                \
        _Pragma("unroll")                                                         \
        for (int j = 0; j < 4; ++j)                                               \
            qf[((s) + 1) & 1][j] = qw[(((s) + 1) * 4 + j) * 64];                  \
    }                                                                             \
    if ((s) + 2 < 8) STAGE_B((s) + 2);                                            \
    bf16x8 kf[4];                                                                 \
    _Pragma("unroll")                                                             \
    for (int i = 0; i < 4; ++i)                                                   \
        kf[i] = *(const bf16x8*)(&Bs[(s) % 3][(wn + i * 16 + l15) * 32 + l4 * 8]);\
    __builtin_amdgcn_s_setprio(1);                                                \
    _Pragma("unroll")                                                             \
    for (int i = 0; i < 4; ++i)                                                   \
        _Pragma("unroll")                                                         \
        for (int j = 0; j < 4; ++j)                                               \
            acc[i][j] = __builtin_amdgcn_mfma_f32_16x16x32_bf16(kf[i], qf[(s) & 1][j], acc[i][j], 0, 0, 0); \
    __builtin_amdgcn_s_setprio(0);                                                \
} while (0)

    // prologue: qf step 0 first (older than stages in vmcnt queue), then B 0,1
#pragma unroll
    for (int j = 0; j < 4; ++j) qf[0][j] = qw[j * 64];
    STAGE_B(0); STAGE_B(1);

    STEP(0, 1); STEP(1, 1); STEP(2, 1); STEP(3, 1);
    STEP(4, 1); STEP(5, 1); STEP(6, 1); STEP(7, 0);

#undef STEP
#undef STAGE_B

    // epilogue: within acc[i][j]: mem = n0+wn+i*16+l4*4+reg, batch = b0+wm+j*16+l15
    float4 Lv[4];
#pragma unroll
    for (int i = 0; i < 4; ++i)
        Lv[i] = *(const float4*)&Ltab[n0 + wn + i * 16 + l4 * 4];
#pragma unroll
    for (int j = 0; j < 4; ++j) {
        const int rb = b0 + wm + j * 16 + l15;
        const size_t row = (size_t)rb * MSIZE;
        unsigned int mlo = 0, mhi = 0;   // 64-bit mask for cols [wn, wn+64) of row rb
#pragma unroll
        for (int i = 0; i < 4; ++i) {
            const float* lv = (const float*)&Lv[i];
            const int nb = n0 + wn + i * 16 + l4 * 4;
            unsigned int pk = 0;
#pragma unroll
            for (int reg = 0; reg < 4; ++reg) {
                float x = fmaf(acc[i][j][reg], KSC, lv[reg]);
                x = fminf(fmaxf(x, 0.0f), 255.0f);
                pk |= (unsigned int)(int)x << (8 * reg);
            }
            *(unsigned int*)(s8 + row + nb) = pk;
            // bit (i*16 + l4*4 + reg) = (byte nb+reg >= 128)
            unsigned int nib = ((pk >> 7) & 1u) | ((pk >> 14) & 2u) |
                               ((pk >> 21) & 4u) | ((pk >> 28) & 8u);
            if (i < 2) mlo |= nib << (i * 16 + l4 * 4);
            else       mhi |= nib << ((i - 2) * 16 + l4 * 4);
        }
        // OR across the 4-lane l4 group (lane ^16, ^32), store once per group
        mlo |= __shfl_xor(mlo, 16, 64); mhi |= __shfl_xor(mhi, 16, 64);
        mlo |= __shfl_xor(mlo, 32, 64); mhi |= __shfl_xor(mhi, 32, 64);
        if (l4 == 0)
            gmask[(size_t)rb * (MSIZE / 64) + ((n0 + wn) >> 6)] =
                ((unsigned long long)mhi << 32) | mlo;
    }
}

// -------------------------------------------------------------------------
// Kernel 2: per batch row.
//   FAST PATH: read 8 KB mask (4 u64/thread), ctz-walk ~2300 set bits,
//   fetch those bytes from L3-resident s8, build LDS candidate list +
//   histogram (no 64 KB stream, no word extraction). Suffix-scan -> H,
//   collect list entries >= H.
//   DENSE FALLBACK (list < SELK or overflow): full-stream histogram +
//   collect over dense s8 (sound for any data).
//   Then: 16-lane-group exact fp32 rescore; count-based exact top-128
//   (ties -> lower index); weighted sum. Selection semantics unchanged.
// -------------------------------------------------------------------------
__global__ __launch_bounds__(256, 4)
void select_kernel(const float* __restrict__ q,
                   const float* __restrict__ key,
                   const float* __restrict__ hist,
                   const float* __restrict__ vals,
                   const unsigned char* __restrict__ s8,
                   const unsigned long long* __restrict__ gmask,
                   float* __restrict__ out)
{
    const int b   = blockIdx.x;
    const int tid = threadIdx.x;

    __shared__ __align__(16) float qs[KDIM];
    __shared__ unsigned int hcnt[8 * 257];    // 8 replicated histograms
    __shared__ int   stot[256];
    __shared__ int   scal[3];                 // 0:H  1:ncand  2:nclist
    __shared__ unsigned int clist[CLCAP];     // (byte<<16 | idx)
    __shared__ int   cidx[1024];
    __shared__ float csc[1024], cjj[1024], cjv[1024];
    __shared__ float wred[8];

    qs[tid] = q[(size_t)b * KDIM + tid];
    const unsigned char* s8row = s8 + (size_t)b * MSIZE;
    const unsigned long long* gm = gmask + (size_t)b * (MSIZE / 64);
    const int rep = (tid & 7) * 257;

    for (int i = tid; i < 8 * 257; i += 256) hcnt[i] = 0u;
    if (tid == 0) { scal[0] = -1; scal[1] = 0; scal[2] = 0; }
    __syncthreads();

    // ---- fast path: mask-driven candidate gather + histogram ----
    for (int k = tid; k < MSIZE / 64; k += 256) {
        unsigned long long m = gm[k];
        while (m) {
            int bpos = __builtin_ctzll(m);
            m &= m - 1;
            int idx = k * 64 + bpos;
            unsigned int by = s8row[idx];
            int p = atomicAdd(&scal[2], 1);
            if (p < CLCAP) clist[p] = (by << 16) | (unsigned int)idx;
            atomicAdd(&hcnt[rep + by], 1u);
        }
    }
    __syncthreads();
    const int ncl = scal[2];
    int mode = (ncl >= SELK && ncl <= CLCAP) ? 0 : 1;
    int H = -1;

    for (;;) {
        if (mode == 1) {   // dense fallback: rebuild full histogram from s8
            __syncthreads();
            for (int i = tid; i < 8 * 257; i += 256) hcnt[i] = 0u;
            if (tid == 0) { scal[0] = -1; scal[1] = 0; }
            __syncthreads();
            const uint4* rowp = reinterpret_cast<const uint4*>(s8row);
            for (int i = 0; i < 16; ++i) {
                uint4 v = rowp[i * 256 + tid];
                unsigned int w[4] = {v.x, v.y, v.z, v.w};
#pragma unroll
                for (int k = 0; k < 4; ++k)
#pragma unroll
                    for (int jj = 0; jj < 4; ++jj)
                        atomicAdd(&hcnt[rep + ((w[k] >> (8 * jj)) & 0xffu)], 1u);
            }
            __syncthreads();
        }
        // suffix-scan over 256 bins; find crossing S[b]>=SELK>S[b+1]
        { unsigned int t = 0;
#pragma unroll
          for (int k = 0; k < 8; ++k) t += hcnt[k * 257 + tid];
          stot[tid] = (int)t; }
        __syncthreads();
        if (tid < 64) {
            const int l = tid;
            int t0 = stot[l * 4], t1 = stot[l * 4 + 1], t2 = stot[l * 4 + 2], t3 = stot[l * 4 + 3];
            int lsum = t0 + t1 + t2 + t3;
            int s = lsum;
#pragma unroll
            for (int off = 1; off < 64; off <<= 1) {
                int u = __shfl_down(s, off, 64);
                if (l + off < 64) s += u;
            }
            int A  = s - lsum;        // sum over lanes > l
            int S3 = A + t3;
            int S2 = S3 + t2;
            int S1 = S2 + t1;
            int S0 = S1 + t0;
            if (S0 >= SELK && S1 < SELK) scal[0] = l * 4 + 0;
            if (S1 >= SELK && S2 < SELK) scal[0] = l * 4 + 1;
            if (S2 >= SELK && S3 < SELK) scal[0] = l * 4 + 2;
            if (S3 >= SELK && A  < SELK) scal[0] = l * 4 + 3;
        }
        __syncthreads();
        H = scal[0];
        __syncthreads();
        if (H >= 0) break;
        mode = 1;                     // fast-path hist had no crossing: go dense
    }

    // ---- collect candidates (byte >= H) ----
    const unsigned int uH = (unsigned int)H;
    if (mode == 0) {
        for (int i = tid; i < ncl; i += 256) {
            unsigned int e = clist[i];
            if ((e >> 16) >= uH) {
                int p = atomicAdd(&scal[1], 1);
                if (p < 1024) cidx[p] = (int)(e & 0xffffu);
            }
        }
    } else {
        const uint4* rowp = reinterpret_cast<const uint4*>(s8row);
        for (int i = 0; i < 16; ++i) {
            uint4 v = rowp[i * 256 + tid];
            const int base = (i * 256 + tid) * 16;
            unsigned int w[4] = {v.x, v.y, v.z, v.w};
#pragma unroll
            for (int k = 0; k < 4; ++k)
#pragma unroll
                for (int jj = 0; jj < 4; ++jj) {
                    unsigned int bb = (w[k] >> (8 * jj)) & 0xffu;
                    if (bb >= uH) {
                        int p = atomicAdd(&scal[1], 1);
                        if (p < 1024) cidx[p] = base + 4 * k + jj;
                    }
                }
        }
    }
    __syncthreads();
    const int ncand = min(scal[1], 1024);

    // ---- exact fp32 rescore: 16-lane groups, 4 candidates per wave in flight ----
    const int gid = tid >> 4, gll = tid & 15;
    const float4* q4 = (const float4*)qs;
    for (int i = gid; i < ncand; i += 16) {
        const int idx = cidx[i];
        const float4* kp = (const float4*)(key + (size_t)idx * KDIM);
        float p = 0.f;
#pragma unroll
        for (int u = 0; u < 4; ++u) {
            float4 kk = kp[gll * 4 + u];
            float4 qq = q4[gll * 4 + u];
            p += kk.x * qq.x + kk.y * qq.y + kk.z * qq.z + kk.w * qq.w;
        }
#pragma unroll
        for (int off = 1; off < 16; off <<= 1) p += __shfl_xor(p, off, 64);
        if (gll == 0) {
            float e = expf(p - 1.0f);
            float h = hist[idx];
            csc[i] = e * (h + BETA);
            float j = e * (ALPHA * h + BETA);
            cjj[i] = j;
            cjv[i] = j * vals[idx];
        }
    }
    __syncthreads();

    // ---- exact top-128 among candidates (count-based; ties -> lower index) ----
    const int wave = tid >> 6, lane = tid & 63;
    float pn = 0.f, pd = 0.f;
    for (int i = tid; i < ncand; i += 256) {
        float si = csc[i]; int ii = cidx[i]; int rank = 0;
        for (int t = 0; t < ncand; ++t) {
            float st = csc[t];
            rank += (st > si || (st == si && cidx[t] < ii)) ? 1 : 0;
        }
        if (rank < CHOOSEK) { pn += cjv[i]; pd += cjj[i]; }
    }
#pragma unroll
    for (int off = 32; off > 0; off >>= 1) {
        pn += __shfl_xor(pn, off, 64);
        pd += __shfl_xor(pd, off, 64);
    }
    if (lane == 0) { wred[wave] = pn; wred[4 + wave] = pd; }
    __syncthreads();
    if (tid == 0) {
        float n = wred[0] + wred[1] + wred[2] + wred[3];
        float d = wred[4] + wred[5] + wred[6] + wred[7];
        out[b] = n / d;
    }
}

// -------------------------------------------------------------------------
extern "C" void kernel_launch(void* const* d_in, const int* in_sizes, int n_in,
                              void* d_out, int out_size, void* d_ws, size_t ws_size,
                              hipStream_t stream)
{
    (void)in_sizes; (void)n_in; (void)out_size; (void)ws_size;
    const float* q    = (const float*)d_in[0];
    const float* key  = (const float*)d_in[1];
    const float* hist = (const float*)d_in[2];
    const float* vals = (const float*)d_in[3];
    float* out = (float*)d_out;

    // workspace layout (105 MiB total):
    unsigned char*  s8 = (unsigned char*)d_ws;                                     // 64 MiB dense u8 keys
    unsigned short* kb = (unsigned short*)((char*)d_ws + ((size_t)64 << 20));      // 32 MiB bf16 key
    unsigned short* qsw= (unsigned short*)((char*)d_ws + ((size_t)96 << 20));      // 512 KiB bf16 q (frag order)
    float*          Lt = (float*)((char*)d_ws + ((size_t)96 << 20) + (512 << 10)); // 256 KiB L table
    unsigned long long* gmask = (unsigned long long*)((char*)d_ws + ((size_t)97 << 20)); // 8 MiB bitmask

    convert_kernel<<<8576, 256, 0, stream>>>(q, key, hist, qsw, kb, Lt);
    score_kernel<<<2048, 512, 0, stream>>>(qsw, kb, Lt, s8, gmask);
    select_kernel<<<BATCH, 256, 0, stream>>>(q, key, hist, vals, s8, gmask, out);
}